// Round 10
// baseline (340.575 us; speedup 1.0000x reference)
//
#include <hip/hip_runtime.h>

#define D 64

// ===========================================================================
// disen_weight = softmax(disen_weight_att, axis=-1) @ relation_emb   [F, D]
// ===========================================================================
__global__ void disen_kernel(const float* __restrict__ att,   // [F, R]
                             const float* __restrict__ rel,   // [R, D]
                             float* __restrict__ disen,       // [F, D]
                             int nF, int nRel) {
    int d = threadIdx.x;
    if (d >= D) return;
    for (int f = 0; f < nF; ++f) {
        float m = -1e30f;
        for (int r = 0; r < nRel; ++r) m = fmaxf(m, att[f * nRel + r]);
        float sum = 0.0f, w = 0.0f;
        for (int r = 0; r < nRel; ++r) {
            float ex = __expf(att[f * nRel + r] - m);
            sum += ex;
            w   += ex * rel[r * D + d];
        }
        disen[f * D + d] = w / sum;
    }
}

// ===========================================================================
// entity_emb f32 -> bf16 (RNE). Halves the random-gather bytes in agg_all.
// ===========================================================================
__global__ void ent_to_bf16(const float* __restrict__ ent,
                            unsigned short* __restrict__ entb, int total) {
    int i = blockIdx.x * blockDim.x + threadIdx.x;
    if (i >= total) return;
    unsigned int u = __float_as_uint(ent[i]);
    u = u + 0x7FFFu + ((u >> 16) & 1u);        // round-to-nearest-even
    entb[i] = (unsigned short)(u >> 16);
}

__device__ __forceinline__ float bf16_to_f32(unsigned short h) {
    return __uint_as_float(((unsigned int)h) << 16);
}

// ===========================================================================
// Lock-free linked lists, 4 chains per row (edge-index & 3).
// 1 divergent op per item (atomicExch); meta stored COALESCED at node index:
//   KG:   int2{prev, tail | type<<20}   -> 1 random line per hop in the walk
//   user: int4{prev, col, val_bits, 0}
// ===========================================================================
__global__ void fill_links(const int* __restrict__ eidx,   // [2, nE]
                           const int* __restrict__ etype,  // [nE]
                           int nE,
                           const int* __restrict__ irows,  // [nnz]
                           const int* __restrict__ icols,  // [nnz]
                           const float* __restrict__ vals, // [nnz]
                           int nnz,                         // (R9 fix: was missing)
                           int* __restrict__ head_e,       // [4*nEnt], init -1
                           int2* __restrict__ meta_e,      // [nE]
                           int* __restrict__ head_u,       // [4*nU], init -1
                           int4* __restrict__ meta_u,      // [nnz]
                           int quarter) {
    int i = blockIdx.x * blockDim.x + threadIdx.x;
    if (i >= quarter) return;   // hard bound (R6 lesson)
#pragma unroll
    for (int k = 0; k < 4; ++k) {
        int e = i + k * quarter;   // disjoint segments cover [0, max(nE,nnz))
        if (e < nE) {
            int h = eidx[e];
            int p = atomicExch(&head_e[4 * h + (e & 3)], e);   // divergent
            meta_e[e] = make_int2(p, eidx[nE + e] | (etype[e] << 20));  // coalesced
        }
        if (e < nnz) {
            int r = irows[e];
            int p = atomicExch(&head_u[4 * r + (e & 3)], e);
            meta_u[e] = make_int4(p, icols[e], __float_as_int(vals[e]), 0);
        }
    }
}

// ===========================================================================
// Fused aggregation: wave per output row (entities then users), lane = dim.
// 4 interleaved chains per row; per hop: 1 packed meta load + 1 bf16 gather.
// Every output element written exactly once.
// ===========================================================================
__global__ void agg_all(const unsigned short* __restrict__ entb,  // bf16 [nEnt*D]
                        const float* __restrict__ rel,
                        const int* __restrict__ head_e, const int2* __restrict__ meta_e,
                        const int* __restrict__ head_u, const int4* __restrict__ meta_u,
                        const float* __restrict__ uemb, const float* __restrict__ lat,
                        const float* __restrict__ disen,
                        float* __restrict__ eagg, float* __restrict__ uagg,
                        int nEnt, int nU) {
    int gid = blockIdx.x * blockDim.x + threadIdx.x;
    int row = gid >> 6;
    int d = gid & 63;

    if (row < nEnt) {
        int e0 = head_e[4 * row];
        int e1 = head_e[4 * row + 1];
        int e2 = head_e[4 * row + 2];
        int e3 = head_e[4 * row + 3];
        float a0 = 0.f, a1 = 0.f, a2 = 0.f, a3 = 0.f;
        int c = 0;
        while (e0 >= 0 || e1 >= 0 || e2 >= 0 || e3 >= 0) {
            if (e0 >= 0) {
                int2 m = meta_e[e0];
                unsigned pp = (unsigned)m.y;
                a0 += bf16_to_f32(entb[(size_t)(pp & 0xFFFFF) * D + d]) *
                      rel[(pp >> 20) * D + d];
                ++c; e0 = m.x;
            }
            if (e1 >= 0) {
                int2 m = meta_e[e1];
                unsigned pp = (unsigned)m.y;
                a1 += bf16_to_f32(entb[(size_t)(pp & 0xFFFFF) * D + d]) *
                      rel[(pp >> 20) * D + d];
                ++c; e1 = m.x;
            }
            if (e2 >= 0) {
                int2 m = meta_e[e2];
                unsigned pp = (unsigned)m.y;
                a2 += bf16_to_f32(entb[(size_t)(pp & 0xFFFFF) * D + d]) *
                      rel[(pp >> 20) * D + d];
                ++c; e2 = m.x;
            }
            if (e3 >= 0) {
                int2 m = meta_e[e3];
                unsigned pp = (unsigned)m.y;
                a3 += bf16_to_f32(entb[(size_t)(pp & 0xFFFFF) * D + d]) *
                      rel[(pp >> 20) * D + d];
                ++c; e3 = m.x;
            }
        }
        eagg[(size_t)row * D + d] = ((a0 + a1) + (a2 + a3)) / fmaxf((float)c, 1.0f);
        return;
    }

    int u = row - nEnt;
    if (u >= nU) return;

    int e0 = head_u[4 * u];
    int e1 = head_u[4 * u + 1];
    int e2 = head_u[4 * u + 2];
    int e3 = head_u[4 * u + 3];
    float a0 = 0.f, a1 = 0.f, a2 = 0.f, a3 = 0.f;
    while (e0 >= 0 || e1 >= 0 || e2 >= 0 || e3 >= 0) {
        if (e0 >= 0) {
            int4 m = meta_u[e0];
            a0 += bf16_to_f32(entb[(size_t)m.y * D + d]) * __int_as_float(m.z);
            e0 = m.x;
        }
        if (e1 >= 0) {
            int4 m = meta_u[e1];
            a1 += bf16_to_f32(entb[(size_t)m.y * D + d]) * __int_as_float(m.z);
            e1 = m.x;
        }
        if (e2 >= 0) {
            int4 m = meta_u[e2];
            a2 += bf16_to_f32(entb[(size_t)m.y * D + d]) * __int_as_float(m.z);
            e2 = m.x;
        }
        if (e3 >= 0) {
            int4 m = meta_u[e3];
            a3 += bf16_to_f32(entb[(size_t)m.y * D + d]) * __int_as_float(m.z);
            e3 = m.x;
        }
    }
    float agg = (a0 + a1) + (a2 + a3);

    // score = softmax_f( dot(uemb[u], lat[f]) ) via full-wave shuffle reduce
    float e = uemb[(size_t)u * D + d];
    float s[4];
#pragma unroll
    for (int f = 0; f < 4; ++f) {
        float p = e * lat[f * D + d];
#pragma unroll
        for (int off = 32; off > 0; off >>= 1) p += __shfl_xor(p, off, 64);
        s[f] = p;
    }
    float m = fmaxf(fmaxf(s[0], s[1]), fmaxf(s[2], s[3]));
    float sum = 0.0f;
#pragma unroll
    for (int f = 0; f < 4; ++f) { s[f] = __expf(s[f] - m); sum += s[f]; }
    float inv = 1.0f / sum;
    float w = 0.0f;
#pragma unroll
    for (int f = 0; f < 4; ++f) w += (s[f] * inv) * disen[f * D + d];

    uagg[(size_t)u * D + d] = w * agg + agg;
}

// ===========================================================================
// FALLBACK: direct atomic scatter (round-3 proven path)
// ===========================================================================
__global__ void kg_scatter(const float* __restrict__ ent, const float* __restrict__ rel,
                           const int* __restrict__ eidx, const int* __restrict__ etype,
                           float* __restrict__ eagg, float* __restrict__ cnt, int nE) {
    int gid = blockIdx.x * blockDim.x + threadIdx.x;
    int e = gid >> 6;
    if (e >= nE) return;
    int d = gid & 63;
    int head = eidx[e];
    int tail = eidx[nE + e];
    int t = etype[e];
    float v = ent[tail * D + d] * rel[t * D + d];
    atomicAdd(&eagg[(size_t)head * D + d], v);
    if (d == 0) atomicAdd(&cnt[head], 1.0f);
}

__global__ void spmm_scatter(const float* __restrict__ ent, const float* __restrict__ vals,
                             const int* __restrict__ rows, const int* __restrict__ cols,
                             float* __restrict__ uagg, int nnz) {
    int gid = blockIdx.x * blockDim.x + threadIdx.x;
    int i = gid >> 6;
    if (i >= nnz) return;
    int d = gid & 63;
    float v = ent[cols[i] * D + d] * vals[i];
    atomicAdd(&uagg[(size_t)rows[i] * D + d], v);
}

__global__ void ent_norm(float* __restrict__ eagg, const float* __restrict__ cnt,
                         int total) {
    int gid = blockIdx.x * blockDim.x + threadIdx.x;
    if (gid >= total) return;
    float c = cnt[gid >> 6];
    eagg[gid] /= fmaxf(c, 1.0f);
}

__global__ void user_final(const float* __restrict__ uemb, const float* __restrict__ lat,
                           const float* __restrict__ disen, float* __restrict__ uagg,
                           int nU) {
    int gid = blockIdx.x * blockDim.x + threadIdx.x;
    int u = gid >> 6;
    if (u >= nU) return;
    int d = gid & 63;
    float e = uemb[(size_t)u * D + d];
    float s[4];
#pragma unroll
    for (int f = 0; f < 4; ++f) {
        float p = e * lat[f * D + d];
#pragma unroll
        for (int off = 32; off > 0; off >>= 1) p += __shfl_xor(p, off, 64);
        s[f] = p;
    }
    float m = fmaxf(fmaxf(s[0], s[1]), fmaxf(s[2], s[3]));
    float sum = 0.0f;
#pragma unroll
    for (int f = 0; f < 4; ++f) { s[f] = __expf(s[f] - m); sum += s[f]; }
    float inv = 1.0f / sum;
    float w = 0.0f;
#pragma unroll
    for (int f = 0; f < 4; ++f) w += (s[f] * inv) * disen[f * D + d];
    size_t o = (size_t)u * D + d;
    float base = uagg[o];
    uagg[o] = w * base + base;
}

// ===========================================================================
extern "C" void kernel_launch(void* const* d_in, const int* in_sizes, int n_in,
                              void* d_out, int out_size, void* d_ws, size_t ws_size,
                              hipStream_t stream) {
    const float* ent   = (const float*)d_in[0];
    const float* uemb  = (const float*)d_in[1];
    const float* lat   = (const float*)d_in[2];
    const float* rel   = (const float*)d_in[3];
    const float* att   = (const float*)d_in[4];
    const float* vals  = (const float*)d_in[5];
    const int*   eidx  = (const int*)d_in[6];
    const int*   etype = (const int*)d_in[7];
    const int*   irows = (const int*)d_in[8];
    const int*   icols = (const int*)d_in[9];

    int nEnt = in_sizes[0] / D;
    int nU   = in_sizes[1] / D;
    int nF   = in_sizes[2] / D;
    int nRel = in_sizes[3] / D;
    int nnz  = in_sizes[5];
    int nE   = in_sizes[6] / 2;

    float* eagg = (float*)d_out;
    float* uagg = (float*)d_out + (size_t)nEnt * D;

    // ---- workspace carve (256B-aligned) ----
    char* base = (char*)d_ws;
    size_t off = 0;
    auto carve = [&](size_t bytes) -> void* {
        void* r = base + off;
        off = (off + bytes + 255) & ~(size_t)255;
        return r;
    };
    float*          disen  = (float*)carve((size_t)nF * D * 4);
    unsigned short* entb   = (unsigned short*)carve((size_t)nEnt * D * 2);
    int*            head_e = (int*)carve((size_t)4 * nEnt * 4);
    int*            head_u = (int*)carve((size_t)4 * nU * 4);
    int2*           meta_e = (int2*)carve((size_t)nE * 8);
    int4*           meta_u = (int4*)carve((size_t)nnz * 16);
    size_t need = off;

    // packing limits: tail < 2^20, type shifts into bits [20,31)
    bool fast = (ws_size >= need) && (nF == 4) && (nEnt <= (1 << 20)) && (nRel <= 2047);

    if (fast) {
        // heads -> -1; single memset spans head_e..head_u (meta needs no init)
        size_t head_span = (size_t)((char*)meta_e - (char*)head_e);
        hipMemsetAsync(head_e, 0xFF, head_span, stream);

        disen_kernel<<<1, 64, 0, stream>>>(att, rel, disen, nF, nRel);

        {
            int total = nEnt * D;
            ent_to_bf16<<<(total + 255) / 256, 256, 0, stream>>>(ent, entb, total);
        }

        int mx = (nE > nnz) ? nE : nnz;
        int quarter = (mx + 3) / 4;
        fill_links<<<(quarter + 255) / 256, 256, 0, stream>>>(
            eidx, etype, nE, irows, icols, vals, nnz,
            head_e, meta_e, head_u, meta_u, quarter);

        long long rows = (long long)nEnt + nU;
        long long tot = rows * 64;
        agg_all<<<(int)((tot + 255) / 256), 256, 0, stream>>>(
            entb, rel, head_e, meta_e, head_u, meta_u,
            uemb, lat, disen, eagg, uagg, nEnt, nU);
        return;
    }

    // ---- fallback: direct atomics (round-3 proven path) ----
    {
        float* cnt = (float*)d_ws;
        size_t cnt_bytes = (((size_t)nEnt * sizeof(float)) + 255) & ~(size_t)255;
        float* disen3 = (float*)((char*)d_ws + cnt_bytes);

        hipMemsetAsync(d_out, 0, (size_t)out_size * sizeof(float), stream);
        hipMemsetAsync(cnt, 0, (size_t)nEnt * sizeof(float), stream);

        disen_kernel<<<1, 64, 0, stream>>>(att, rel, disen3, nF, nRel);
        {
            long long total = (long long)nE * 64;
            kg_scatter<<<(int)((total + 255) / 256), 256, 0, stream>>>(
                ent, rel, eidx, etype, eagg, cnt, nE);
        }
        {
            long long total = (long long)nnz * 64;
            spmm_scatter<<<(int)((total + 255) / 256), 256, 0, stream>>>(
                ent, vals, irows, icols, uagg, nnz);
        }
        {
            int total = nEnt * D;
            ent_norm<<<(total + 255) / 256, 256, 0, stream>>>(eagg, cnt, total);
        }
        {
            long long total = (long long)nU * 64;
            user_final<<<(int)((total + 255) / 256), 256, 0, stream>>>(
                uemb, lat, disen3, uagg, nU);
        }
    }
}

// Round 11
// 311.148 us; speedup vs baseline: 1.0946x; 1.0946x over previous
//
#include <hip/hip_runtime.h>

#define D 64
#define NCH 8   // chains per row

// ===========================================================================
// disen_weight = softmax(disen_weight_att, axis=-1) @ relation_emb   [F, D]
// ===========================================================================
__global__ void disen_kernel(const float* __restrict__ att,   // [F, R]
                             const float* __restrict__ rel,   // [R, D]
                             float* __restrict__ disen,       // [F, D]
                             int nF, int nRel) {
    int d = threadIdx.x;
    if (d >= D) return;
    for (int f = 0; f < nF; ++f) {
        float m = -1e30f;
        for (int r = 0; r < nRel; ++r) m = fmaxf(m, att[f * nRel + r]);
        float sum = 0.0f, w = 0.0f;
        for (int r = 0; r < nRel; ++r) {
            float ex = __expf(att[f * nRel + r] - m);
            sum += ex;
            w   += ex * rel[r * D + d];
        }
        disen[f * D + d] = w / sum;
    }
}

// ===========================================================================
// entity_emb f32 -> bf16 (RNE). Halves the random-gather bytes in agg_all.
// ===========================================================================
__global__ void ent_to_bf16(const float* __restrict__ ent,
                            unsigned short* __restrict__ entb, int total) {
    int i = blockIdx.x * blockDim.x + threadIdx.x;
    if (i >= total) return;
    unsigned int u = __float_as_uint(ent[i]);
    u = u + 0x7FFFu + ((u >> 16) & 1u);        // round-to-nearest-even
    entb[i] = (unsigned short)(u >> 16);
}

__device__ __forceinline__ float bf16_to_f32(unsigned short h) {
    return __uint_as_float(((unsigned int)h) << 16);
}

// ===========================================================================
// Lock-free linked lists, NCH=8 chains per row (edge-index & 7).
// 1 divergent op per item (atomicExch); meta stored COALESCED at node index:
//   KG:   int2{prev, tail | type<<20}
//   user: int4{prev, col, val_bits, 0}
// ===========================================================================
__global__ void fill_links(const int* __restrict__ eidx,   // [2, nE]
                           const int* __restrict__ etype,  // [nE]
                           int nE,
                           const int* __restrict__ irows,  // [nnz]
                           const int* __restrict__ icols,  // [nnz]
                           const float* __restrict__ vals, // [nnz]
                           int nnz,
                           int* __restrict__ head_e,       // [NCH*nEnt], init -1
                           int2* __restrict__ meta_e,      // [nE]
                           int* __restrict__ head_u,       // [NCH*nU], init -1
                           int4* __restrict__ meta_u,      // [nnz]
                           int quarter) {
    int i = blockIdx.x * blockDim.x + threadIdx.x;
    if (i >= quarter) return;   // hard bound (R6 lesson)
#pragma unroll
    for (int k = 0; k < 4; ++k) {
        int e = i + k * quarter;   // disjoint segments cover [0, max(nE,nnz))
        if (e < nE) {
            int h = eidx[e];
            int p = atomicExch(&head_e[NCH * h + (e & (NCH - 1))], e);  // divergent
            meta_e[e] = make_int2(p, eidx[nE + e] | (etype[e] << 20));  // coalesced
        }
        if (e < nnz) {
            int r = irows[e];
            int p = atomicExch(&head_u[NCH * r + (e & (NCH - 1))], e);
            meta_u[e] = make_int4(p, icols[e], __float_as_int(vals[e]), 0);
        }
    }
}

// ===========================================================================
// Fused aggregation: wave per output row, USERS FIRST (long rows start early),
// then entities. lane = dim. NCH interleaved chains per row; row made
// provably wave-uniform via readfirstlane so chain state / meta loads take
// the scalar path (s_load on lgkmcnt), overlapping the vector gathers (vmcnt).
// Every output element written exactly once.
// ===========================================================================
__global__ void agg_all(const unsigned short* __restrict__ entb,  // bf16 [nEnt*D]
                        const float* __restrict__ rel,
                        const int* __restrict__ head_e, const int2* __restrict__ meta_e,
                        const int* __restrict__ head_u, const int4* __restrict__ meta_u,
                        const float* __restrict__ uemb, const float* __restrict__ lat,
                        const float* __restrict__ disen,
                        float* __restrict__ eagg, float* __restrict__ uagg,
                        int nEnt, int nU) {
    int gid = blockIdx.x * blockDim.x + threadIdx.x;
    int row = __builtin_amdgcn_readfirstlane(gid >> 6);   // wave-uniform, provable
    int d = gid & 63;

    if (row < nU) {
        // ---------------- user row ----------------
        int u = row;
        int ech[NCH];
        float acc[NCH];
#pragma unroll
        for (int k = 0; k < NCH; ++k) {
            ech[k] = head_u[NCH * u + k];
            acc[k] = 0.0f;
        }
        bool any = true;
        while (any) {
            any = false;
#pragma unroll
            for (int k = 0; k < NCH; ++k) {
                if (ech[k] >= 0) {
                    int4 m = meta_u[ech[k]];
                    acc[k] += bf16_to_f32(entb[(size_t)m.y * D + d]) *
                              __int_as_float(m.z);
                    ech[k] = m.x;
                    any = true;
                }
            }
        }
        float agg = ((acc[0] + acc[1]) + (acc[2] + acc[3])) +
                    ((acc[4] + acc[5]) + (acc[6] + acc[7]));

        // score = softmax_f( dot(uemb[u], lat[f]) ) via full-wave shuffle reduce
        float e = uemb[(size_t)u * D + d];
        float s[4];
#pragma unroll
        for (int f = 0; f < 4; ++f) {
            float p = e * lat[f * D + d];
#pragma unroll
            for (int off = 32; off > 0; off >>= 1) p += __shfl_xor(p, off, 64);
            s[f] = p;
        }
        float m = fmaxf(fmaxf(s[0], s[1]), fmaxf(s[2], s[3]));
        float sum = 0.0f;
#pragma unroll
        for (int f = 0; f < 4; ++f) { s[f] = __expf(s[f] - m); sum += s[f]; }
        float inv = 1.0f / sum;
        float w = 0.0f;
#pragma unroll
        for (int f = 0; f < 4; ++f) w += (s[f] * inv) * disen[f * D + d];

        uagg[(size_t)u * D + d] = w * agg + agg;
        return;
    }

    // ---------------- entity row ----------------
    int er = row - nU;
    if (er >= nEnt) return;

    int ech[NCH];
    float acc[NCH];
#pragma unroll
    for (int k = 0; k < NCH; ++k) {
        ech[k] = head_e[NCH * er + k];
        acc[k] = 0.0f;
    }
    int c = 0;
    bool any = true;
    while (any) {
        any = false;
#pragma unroll
        for (int k = 0; k < NCH; ++k) {
            if (ech[k] >= 0) {
                int2 m = meta_e[ech[k]];
                unsigned pp = (unsigned)m.y;
                acc[k] += bf16_to_f32(entb[(size_t)(pp & 0xFFFFF) * D + d]) *
                          rel[(pp >> 20) * D + d];
                ++c;
                ech[k] = m.x;
                any = true;
            }
        }
    }
    float tot = ((acc[0] + acc[1]) + (acc[2] + acc[3])) +
                ((acc[4] + acc[5]) + (acc[6] + acc[7]));
    eagg[(size_t)er * D + d] = tot / fmaxf((float)c, 1.0f);
}

// ===========================================================================
// FALLBACK: direct atomic scatter (round-3 proven path)
// ===========================================================================
__global__ void kg_scatter(const float* __restrict__ ent, const float* __restrict__ rel,
                           const int* __restrict__ eidx, const int* __restrict__ etype,
                           float* __restrict__ eagg, float* __restrict__ cnt, int nE) {
    int gid = blockIdx.x * blockDim.x + threadIdx.x;
    int e = gid >> 6;
    if (e >= nE) return;
    int d = gid & 63;
    int head = eidx[e];
    int tail = eidx[nE + e];
    int t = etype[e];
    float v = ent[tail * D + d] * rel[t * D + d];
    atomicAdd(&eagg[(size_t)head * D + d], v);
    if (d == 0) atomicAdd(&cnt[head], 1.0f);
}

__global__ void spmm_scatter(const float* __restrict__ ent, const float* __restrict__ vals,
                             const int* __restrict__ rows, const int* __restrict__ cols,
                             float* __restrict__ uagg, int nnz) {
    int gid = blockIdx.x * blockDim.x + threadIdx.x;
    int i = gid >> 6;
    if (i >= nnz) return;
    int d = gid & 63;
    float v = ent[cols[i] * D + d] * vals[i];
    atomicAdd(&uagg[(size_t)rows[i] * D + d], v);
}

__global__ void ent_norm(float* __restrict__ eagg, const float* __restrict__ cnt,
                         int total) {
    int gid = blockIdx.x * blockDim.x + threadIdx.x;
    if (gid >= total) return;
    float c = cnt[gid >> 6];
    eagg[gid] /= fmaxf(c, 1.0f);
}

__global__ void user_final(const float* __restrict__ uemb, const float* __restrict__ lat,
                           const float* __restrict__ disen, float* __restrict__ uagg,
                           int nU) {
    int gid = blockIdx.x * blockDim.x + threadIdx.x;
    int u = gid >> 6;
    if (u >= nU) return;
    int d = gid & 63;
    float e = uemb[(size_t)u * D + d];
    float s[4];
#pragma unroll
    for (int f = 0; f < 4; ++f) {
        float p = e * lat[f * D + d];
#pragma unroll
        for (int off = 32; off > 0; off >>= 1) p += __shfl_xor(p, off, 64);
        s[f] = p;
    }
    float m = fmaxf(fmaxf(s[0], s[1]), fmaxf(s[2], s[3]));
    float sum = 0.0f;
#pragma unroll
    for (int f = 0; f < 4; ++f) { s[f] = __expf(s[f] - m); sum += s[f]; }
    float inv = 1.0f / sum;
    float w = 0.0f;
#pragma unroll
    for (int f = 0; f < 4; ++f) w += (s[f] * inv) * disen[f * D + d];
    size_t o = (size_t)u * D + d;
    float base = uagg[o];
    uagg[o] = w * base + base;
}

// ===========================================================================
extern "C" void kernel_launch(void* const* d_in, const int* in_sizes, int n_in,
                              void* d_out, int out_size, void* d_ws, size_t ws_size,
                              hipStream_t stream) {
    const float* ent   = (const float*)d_in[0];
    const float* uemb  = (const float*)d_in[1];
    const float* lat   = (const float*)d_in[2];
    const float* rel   = (const float*)d_in[3];
    const float* att   = (const float*)d_in[4];
    const float* vals  = (const float*)d_in[5];
    const int*   eidx  = (const int*)d_in[6];
    const int*   etype = (const int*)d_in[7];
    const int*   irows = (const int*)d_in[8];
    const int*   icols = (const int*)d_in[9];

    int nEnt = in_sizes[0] / D;
    int nU   = in_sizes[1] / D;
    int nF   = in_sizes[2] / D;
    int nRel = in_sizes[3] / D;
    int nnz  = in_sizes[5];
    int nE   = in_sizes[6] / 2;

    float* eagg = (float*)d_out;
    float* uagg = (float*)d_out + (size_t)nEnt * D;

    // ---- workspace carve (256B-aligned) ----
    char* base = (char*)d_ws;
    size_t off = 0;
    auto carve = [&](size_t bytes) -> void* {
        void* r = base + off;
        off = (off + bytes + 255) & ~(size_t)255;
        return r;
    };
    float*          disen  = (float*)carve((size_t)nF * D * 4);
    unsigned short* entb   = (unsigned short*)carve((size_t)nEnt * D * 2);
    int*            head_e = (int*)carve((size_t)NCH * nEnt * 4);
    int*            head_u = (int*)carve((size_t)NCH * nU * 4);
    int2*           meta_e = (int2*)carve((size_t)nE * 8);
    int4*           meta_u = (int4*)carve((size_t)nnz * 16);
    size_t need = off;

    // packing limits: tail < 2^20, type shifts into bits [20,31)
    bool fast = (ws_size >= need) && (nF == 4) && (nEnt <= (1 << 20)) && (nRel <= 2047);

    if (fast) {
        // heads -> -1; single memset spans head_e..head_u (meta needs no init)
        size_t head_span = (size_t)((char*)meta_e - (char*)head_e);
        hipMemsetAsync(head_e, 0xFF, head_span, stream);

        disen_kernel<<<1, 64, 0, stream>>>(att, rel, disen, nF, nRel);

        {
            int total = nEnt * D;
            ent_to_bf16<<<(total + 255) / 256, 256, 0, stream>>>(ent, entb, total);
        }

        int mx = (nE > nnz) ? nE : nnz;
        int quarter = (mx + 3) / 4;
        fill_links<<<(quarter + 255) / 256, 256, 0, stream>>>(
            eidx, etype, nE, irows, icols, vals, nnz,
            head_e, meta_e, head_u, meta_u, quarter);

        long long rows = (long long)nEnt + nU;
        long long tot = rows * 64;
        agg_all<<<(int)((tot + 255) / 256), 256, 0, stream>>>(
            entb, rel, head_e, meta_e, head_u, meta_u,
            uemb, lat, disen, eagg, uagg, nEnt, nU);
        return;
    }

    // ---- fallback: direct atomics (round-3 proven path) ----
    {
        float* cnt = (float*)d_ws;
        size_t cnt_bytes = (((size_t)nEnt * sizeof(float)) + 255) & ~(size_t)255;
        float* disen3 = (float*)((char*)d_ws + cnt_bytes);

        hipMemsetAsync(d_out, 0, (size_t)out_size * sizeof(float), stream);
        hipMemsetAsync(cnt, 0, (size_t)nEnt * sizeof(float), stream);

        disen_kernel<<<1, 64, 0, stream>>>(att, rel, disen3, nF, nRel);
        {
            long long total = (long long)nE * 64;
            kg_scatter<<<(int)((total + 255) / 256), 256, 0, stream>>>(
                ent, rel, eidx, etype, eagg, cnt, nE);
        }
        {
            long long total = (long long)nnz * 64;
            spmm_scatter<<<(int)((total + 255) / 256), 256, 0, stream>>>(
                ent, vals, irows, icols, uagg, nnz);
        }
        {
            int total = nEnt * D;
            ent_norm<<<(total + 255) / 256, 256, 0, stream>>>(eagg, cnt, total);
        }
        {
            long long total = (long long)nU * 64;
            user_final<<<(int)((total + 255) / 256), 256, 0, stream>>>(
                uemb, lat, disen3, uagg, nU);
        }
    }
}